// Round 1
// baseline (2996.592 us; speedup 1.0000x reference)
//
#include <hip/hip_runtime.h>
#include <hip/hip_bf16.h>

#define N_NODES 50000
#define N_EDGES 1600000
#define N_REL   20
#define N_BASIS 16
#define DIM     128                      // IN == OUT == 128
#define KTOT    ((N_REL + 1) * DIM)      // 2688 : Wt row stride (R rels + self)

typedef __attribute__((ext_vector_type(8))) short          bf16x8;
typedef __attribute__((ext_vector_type(4))) float          f32x4;
typedef __attribute__((ext_vector_type(4))) unsigned short ushort4v;
typedef __attribute__((ext_vector_type(8))) unsigned short ushort8v;

static __device__ __forceinline__ unsigned short f2bf(float f) {
    union { float f; unsigned int u; } v; v.f = f;
    unsigned int r = (v.u + 0x7FFFu + ((v.u >> 16) & 1u)) >> 16;   // RNE
    return (unsigned short)r;
}

// Wt[o][r*128+i] = bf16( sum_b bw[r,b] * bases[b,i,o] ),  r==N_REL -> self_W[o,i]
__global__ void compute_wt(const float* __restrict__ bases,
                           const float* __restrict__ bw,
                           const float* __restrict__ selfW,
                           unsigned short* __restrict__ Wt) {
    int t = blockIdx.x * blockDim.x + threadIdx.x;
    const int total = DIM * (N_REL + 1) * DIM;
    if (t >= total) return;
    int i = t & (DIM - 1);
    int r = (t >> 7) % (N_REL + 1);
    int o = t / (DIM * (N_REL + 1));
    float v;
    if (r < N_REL) {
        v = 0.f;
        #pragma unroll
        for (int b = 0; b < N_BASIS; ++b)
            v += bw[r * N_BASIS + b] * bases[((size_t)b * DIM + i) * DIM + o];
    } else {
        v = selfW[o * DIM + i];
    }
    Wt[(size_t)o * KTOT + r * DIM + i] = f2bf(v);
}

// scatter: agg[dst][rl*128 + i] += x[src][i] / norm[r][dst]   (32 threads/edge x float4)
__global__ void scatter_edges(const float* __restrict__ x,
                              const int* __restrict__ eidx,
                              const int* __restrict__ etype,
                              const float* __restrict__ norm,
                              float* __restrict__ agg,
                              int r0, int rc) {
    int t = blockIdx.x * blockDim.x + threadIdx.x;
    const int total = N_EDGES * 32;
    if (t >= total) return;
    int e  = t >> 5;
    int l4 = t & 31;
    int r  = etype[e];
    int rl = r - r0;
    if ((unsigned)rl >= (unsigned)rc) return;
    int src = eidx[e];
    int dst = eidx[N_EDGES + e];
    float inv = 1.0f / norm[(size_t)r * N_NODES + dst];
    float4 xv = reinterpret_cast<const float4*>(x)[src * 32 + l4];
    float* base = agg + ((size_t)dst * rc + rl) * DIM + l4 * 4;
    unsafeAtomicAdd(base + 0, xv.x * inv);
    unsafeAtomicAdd(base + 1, xv.y * inv);
    unsafeAtomicAdd(base + 2, xv.z * inv);
    unsafeAtomicAdd(base + 3, xv.w * inv);
}

// out[n][o] (+)= sum_k Wt_sub[o*KTOT+k] * Bsrc[n*K+k]
// Transposed product: D rows = o, D cols = n. Both operands K-contiguous -> no transpose staging.
__global__ __launch_bounds__(256) void gemm_t(const unsigned short* __restrict__ Wt_sub,
                                              const float* __restrict__ Bsrc,
                                              int K,
                                              float* __restrict__ C,
                                              int acc_mode) {
    __shared__ __align__(16) unsigned short Ws[128 * 40];  // [o][k] bf16, pad stride 40
    __shared__ __align__(16) unsigned short As[64 * 40];   // [n][k] bf16

    int tid  = threadIdx.x;
    int lane = tid & 63;
    int wv   = tid >> 6;          // 4 waves, each owns 16 n-rows
    int nblock = blockIdx.x * 64;

    f32x4 acc[8];
    #pragma unroll
    for (int i = 0; i < 8; ++i) acc[i] = (f32x4){0.f, 0.f, 0.f, 0.f};

    for (int k0 = 0; k0 < K; k0 += 32) {
        // stage Wt tile: 128 o x 32 k (bf16, straight copy)
        #pragma unroll
        for (int rep = 0; rep < 2; ++rep) {
            int idx = rep * 256 + tid;          // 512 x (8 shorts)
            int o  = idx >> 2;
            int kq = idx & 3;
            ushort8v v = *reinterpret_cast<const ushort8v*>(Wt_sub + (size_t)o * KTOT + k0 + kq * 8);
            *reinterpret_cast<ushort8v*>(&Ws[o * 40 + kq * 8]) = v;
        }
        // stage B tile: 64 n x 32 k (f32 -> bf16)
        #pragma unroll
        for (int rep = 0; rep < 2; ++rep) {
            int idx = rep * 256 + tid;          // 512 x float4
            int n  = idx >> 3;
            int kq = idx & 7;
            int gn = nblock + n;
            float4 v = {0.f, 0.f, 0.f, 0.f};
            if (gn < N_NODES)
                v = *reinterpret_cast<const float4*>(Bsrc + (size_t)gn * K + k0 + kq * 4);
            ushort4v s = { f2bf(v.x), f2bf(v.y), f2bf(v.z), f2bf(v.w) };
            *reinterpret_cast<ushort4v*>(&As[n * 40 + kq * 4]) = s;
        }
        __syncthreads();

        int koff = (lane >> 4) * 8;
        int r16  = lane & 15;
        bf16x8 bfr = *reinterpret_cast<const bf16x8*>(&As[(wv * 16 + r16) * 40 + koff]);
        #pragma unroll
        for (int of = 0; of < 8; ++of) {
            bf16x8 afr = *reinterpret_cast<const bf16x8*>(&Ws[(of * 16 + r16) * 40 + koff]);
            acc[of] = __builtin_amdgcn_mfma_f32_16x16x32_bf16(afr, bfr, acc[of], 0, 0, 0);
        }
        __syncthreads();
    }

    // D mapping: col = lane&15 -> n, row = (lane>>4)*4 + reg -> o
    int n = nblock + wv * 16 + (lane & 15);
    if (n < N_NODES) {
        int obase = (lane >> 4) * 4;
        #pragma unroll
        for (int of = 0; of < 8; ++of) {
            float* p = C + (size_t)n * DIM + of * 16 + obase;
            if (acc_mode) {
                p[0] += acc[of].x; p[1] += acc[of].y; p[2] += acc[of].z; p[3] += acc[of].w;
            } else {
                float4 vv = {acc[of].x, acc[of].y, acc[of].z, acc[of].w};
                *reinterpret_cast<float4*>(p) = vv;
            }
        }
    }
}

extern "C" void kernel_launch(void* const* d_in, const int* in_sizes, int n_in,
                              void* d_out, int out_size, void* d_ws, size_t ws_size,
                              hipStream_t stream) {
    const float* x     = (const float*)d_in[0];
    const int*   eidx  = (const int*)d_in[1];
    const int*   etype = (const int*)d_in[2];
    const float* norm  = (const float*)d_in[3];
    const float* selfW = (const float*)d_in[4];
    const float* bases = (const float*)d_in[5];
    const float* bw    = (const float*)d_in[6];
    float* out = (float*)d_out;

    unsigned short* Wt = (unsigned short*)d_ws;
    size_t wt_bytes = (size_t)DIM * KTOT * sizeof(unsigned short);    // 688128 B
    float* agg = (float*)((char*)d_ws + wt_bytes);
    size_t per_rel = (size_t)N_NODES * DIM * sizeof(float);           // 25.6 MB

    int rc = 5;                                                       // 128 MB agg -> LLC-resident
    size_t avail = (ws_size > wt_bytes) ? (ws_size - wt_bytes) : 0;
    int rc_max = (int)(avail / per_rel);
    if (rc_max < rc) rc = rc_max;
    if (rc < 1) rc = 1;

    {   // 1. build Wt (bf16, transposed, self appended as relation R)
        int total = DIM * (N_REL + 1) * DIM;
        compute_wt<<<dim3((total + 255) / 256), dim3(256), 0, stream>>>(bases, bw, selfW, Wt);
    }

    int gblocks = (N_NODES + 63) / 64;

    // 2. self-loop: out = x @ self_W.T   (init write)
    gemm_t<<<dim3(gblocks), dim3(256), 0, stream>>>(Wt + N_REL * DIM, x, DIM, out, 0);

    // 3. relation chunks: zero agg, scatter, GEMM-accumulate
    for (int r0 = 0; r0 < N_REL; r0 += rc) {
        int rca = (rc < N_REL - r0) ? rc : (N_REL - r0);
        hipMemsetAsync(agg, 0, (size_t)rca * per_rel, stream);
        int total = N_EDGES * 32;
        scatter_edges<<<dim3((total + 255) / 256), dim3(256), 0, stream>>>(
            x, eidx, etype, norm, agg, r0, rca);
        gemm_t<<<dim3(gblocks), dim3(256), 0, stream>>>(Wt + r0 * DIM, agg, rca * DIM, out, 1);
    }
}

// Round 2
// 611.885 us; speedup vs baseline: 4.8973x; 4.8973x over previous
//
#include <hip/hip_runtime.h>
#include <hip/hip_bf16.h>

#define N_NODES 50000
#define N_EDGES 1600000
#define N_REL   20
#define N_BASIS 16
#define DIM     128
#define KTOT    ((N_REL + 1) * DIM)      // 2688 : Wt row stride (R rels + self)

#define RC      5                        // relations per chunk
#define NCHUNK  (N_REL / RC)             // 4
#define NBINS   (NCHUNK * N_NODES)       // 200000 sort bins: key = chunk*N + dst

#define SCAN_T     1024
#define SCAN_ELEMS 4
#define SCAN_CHUNK (SCAN_T * SCAN_ELEMS)                       // 4096
#define SCAN_BLOCKS ((NBINS + SCAN_CHUNK - 1) / SCAN_CHUNK)    // 49

typedef __attribute__((ext_vector_type(8))) short          bf16x8;
typedef __attribute__((ext_vector_type(4))) float          f32x4;
typedef __attribute__((ext_vector_type(8))) unsigned short ushort8v;

static __device__ __forceinline__ unsigned short f2bf(float f) {
    union { float f; unsigned int u; } v; v.f = f;
    unsigned int r = (v.u + 0x7FFFu + ((v.u >> 16) & 1u)) >> 16;   // RNE
    return (unsigned short)r;
}
static __device__ __forceinline__ float bf2f(unsigned short s) {
    union { unsigned int u; float f; } v; v.u = ((unsigned int)s) << 16;
    return v.f;
}

// ---------- prep: Wt[o][r*128+i] bf16 (r==N_REL -> self_W), xb = bf16(x) ----------
__global__ void compute_wt(const float* __restrict__ bases,
                           const float* __restrict__ bw,
                           const float* __restrict__ selfW,
                           unsigned short* __restrict__ Wt) {
    int t = blockIdx.x * blockDim.x + threadIdx.x;
    const int total = DIM * (N_REL + 1) * DIM;
    if (t >= total) return;
    int i = t & (DIM - 1);
    int r = (t >> 7) % (N_REL + 1);
    int o = t / (DIM * (N_REL + 1));
    float v;
    if (r < N_REL) {
        v = 0.f;
        #pragma unroll
        for (int b = 0; b < N_BASIS; ++b)
            v += bw[r * N_BASIS + b] * bases[((size_t)b * DIM + i) * DIM + o];
    } else {
        v = selfW[o * DIM + i];
    }
    Wt[(size_t)o * KTOT + r * DIM + i] = f2bf(v);
}

__global__ void build_xb(const float* __restrict__ x, unsigned short* __restrict__ xb) {
    int t = blockIdx.x * blockDim.x + threadIdx.x;
    const int total = N_NODES * DIM;
    if (t < total) xb[t] = f2bf(x[t]);
}

// ---------- counting sort by key = (etype/RC)*N + dst ----------
__global__ void hist_kernel(const int* __restrict__ eidx, const int* __restrict__ etype,
                            unsigned int* __restrict__ bins) {
    int e = blockIdx.x * blockDim.x + threadIdx.x;
    if (e >= N_EDGES) return;
    int r = etype[e];
    int dst = eidx[N_EDGES + e];
    atomicAdd(&bins[(r / RC) * N_NODES + dst], 1u);
}

__global__ __launch_bounds__(SCAN_T) void scan1(unsigned int* __restrict__ data,
                                                unsigned int* __restrict__ totals) {
    __shared__ unsigned int lds[SCAN_T];
    int t = threadIdx.x;
    int base = blockIdx.x * SCAN_CHUNK + t * SCAN_ELEMS;
    unsigned int v[SCAN_ELEMS];
    unsigned int s = 0;
    #pragma unroll
    for (int i = 0; i < SCAN_ELEMS; ++i) {
        unsigned int x = (base + i < NBINS) ? data[base + i] : 0u;
        v[i] = s; s += x;
    }
    lds[t] = s; __syncthreads();
    for (int off = 1; off < SCAN_T; off <<= 1) {
        unsigned int add = (t >= off) ? lds[t - off] : 0u;
        __syncthreads();
        lds[t] += add;
        __syncthreads();
    }
    unsigned int excl = (t > 0) ? lds[t - 1] : 0u;
    if (t == SCAN_T - 1) totals[blockIdx.x] = lds[t];
    #pragma unroll
    for (int i = 0; i < SCAN_ELEMS; ++i)
        if (base + i < NBINS) data[base + i] = excl + v[i];
}

__global__ void scan2(unsigned int* __restrict__ totals) {
    __shared__ unsigned int lds[64];
    int t = threadIdx.x;
    unsigned int x = (t < SCAN_BLOCKS) ? totals[t] : 0u;
    lds[t] = x; __syncthreads();
    for (int off = 1; off < 64; off <<= 1) {
        unsigned int add = (t >= off) ? lds[t - off] : 0u;
        __syncthreads();
        lds[t] += add;
        __syncthreads();
    }
    if (t < SCAN_BLOCKS) totals[t] = (t > 0) ? lds[t - 1] : 0u;
}

__global__ void scan3(unsigned int* __restrict__ binstart, unsigned int* __restrict__ cursor,
                      const unsigned int* __restrict__ totals) {
    int i = blockIdx.x * blockDim.x + threadIdx.x;
    if (i < NBINS) {
        unsigned int v = binstart[i] + totals[i / SCAN_CHUNK];
        binstart[i] = v;
        cursor[i] = v;
    }
    if (i == 0) binstart[NBINS] = N_EDGES;
}

__global__ void place_kernel(const int* __restrict__ eidx, const int* __restrict__ etype,
                             unsigned int* __restrict__ cursor, unsigned int* __restrict__ sorted) {
    int e = blockIdx.x * blockDim.x + threadIdx.x;
    if (e >= N_EDGES) return;
    int r = etype[e];
    int src = eidx[e];
    int dst = eidx[N_EDGES + e];
    int c = r / RC;
    int rl = r - c * RC;
    unsigned int pos = atomicAdd(&cursor[c * N_NODES + dst], 1u);
    sorted[pos] = (unsigned int)src | ((unsigned int)rl << 16);
}

// ---------- atomic-free segmented reduce: agg[dst][rl*128+i] = bf16( sum x[src][i]/norm ) ----------
__global__ __launch_bounds__(128) void reduce_seg(const unsigned int* __restrict__ sorted,
                                                  const unsigned int* __restrict__ binstart,
                                                  const unsigned short* __restrict__ xb,
                                                  const float* __restrict__ norm,
                                                  unsigned short* __restrict__ agg,
                                                  int chunk) {
    __shared__ float nlds[RC];
    int dst = blockIdx.x;
    int i = threadIdx.x;
    if (i < RC) nlds[i] = 1.0f / norm[(size_t)(chunk * RC + i) * N_NODES + dst];
    int key = chunk * N_NODES + dst;
    unsigned int bs = binstart[key], be = binstart[key + 1];
    __syncthreads();
    float a0 = 0.f, a1 = 0.f, a2 = 0.f, a3 = 0.f, a4 = 0.f;
    for (unsigned int j = bs; j < be; ++j) {
        unsigned int p = sorted[j];
        int src = p & 0xFFFF;
        int rl = p >> 16;
        float v = bf2f(xb[src * DIM + i]) * nlds[rl];
        a0 += (rl == 0) ? v : 0.f;
        a1 += (rl == 1) ? v : 0.f;
        a2 += (rl == 2) ? v : 0.f;
        a3 += (rl == 3) ? v : 0.f;
        a4 += (rl == 4) ? v : 0.f;
    }
    size_t ob = (size_t)dst * (RC * DIM) + i;
    agg[ob]           = f2bf(a0);
    agg[ob + DIM]     = f2bf(a1);
    agg[ob + 2 * DIM] = f2bf(a2);
    agg[ob + 3 * DIM] = f2bf(a3);
    agg[ob + 4 * DIM] = f2bf(a4);
}

// ---------- MFMA GEMM: out[n][o] (+)= sum_k Wt_sub[o*KTOT+k] * Bsrc[n*K+k], Bsrc bf16 ----------
__global__ __launch_bounds__(256) void gemm_bf(const unsigned short* __restrict__ Wt_sub,
                                               const unsigned short* __restrict__ Bsrc,
                                               int K,
                                               float* __restrict__ C,
                                               int acc_mode) {
    __shared__ __align__(16) unsigned short Ws[128 * 40];  // [o][k], pad stride 40
    __shared__ __align__(16) unsigned short As[64 * 40];   // [n][k]

    int tid  = threadIdx.x;
    int lane = tid & 63;
    int wv   = tid >> 6;
    int nblock = blockIdx.x * 64;

    f32x4 acc[8];
    #pragma unroll
    for (int i = 0; i < 8; ++i) acc[i] = (f32x4){0.f, 0.f, 0.f, 0.f};

    for (int k0 = 0; k0 < K; k0 += 32) {
        #pragma unroll
        for (int rep = 0; rep < 2; ++rep) {          // Wt tile: 128 o x 32 k
            int idx = rep * 256 + tid;
            int o  = idx >> 2;
            int kq = idx & 3;
            ushort8v v = *reinterpret_cast<const ushort8v*>(Wt_sub + (size_t)o * KTOT + k0 + kq * 8);
            *reinterpret_cast<ushort8v*>(&Ws[o * 40 + kq * 8]) = v;
        }
        {                                            // B tile: 64 n x 32 k (bf16 straight copy)
            int n  = tid >> 2;
            int kq = tid & 3;
            int gn = nblock + n;
            ushort8v v = (ushort8v){0,0,0,0,0,0,0,0};
            if (gn < N_NODES)
                v = *reinterpret_cast<const ushort8v*>(Bsrc + (size_t)gn * K + k0 + kq * 8);
            *reinterpret_cast<ushort8v*>(&As[n * 40 + kq * 8]) = v;
        }
        __syncthreads();

        int koff = (lane >> 4) * 8;
        int r16  = lane & 15;
        bf16x8 bfr = *reinterpret_cast<const bf16x8*>(&As[(wv * 16 + r16) * 40 + koff]);
        #pragma unroll
        for (int of = 0; of < 8; ++of) {
            bf16x8 afr = *reinterpret_cast<const bf16x8*>(&Ws[(of * 16 + r16) * 40 + koff]);
            acc[of] = __builtin_amdgcn_mfma_f32_16x16x32_bf16(afr, bfr, acc[of], 0, 0, 0);
        }
        __syncthreads();
    }

    int n = nblock + wv * 16 + (lane & 15);
    if (n < N_NODES) {
        int obase = (lane >> 4) * 4;
        #pragma unroll
        for (int of = 0; of < 8; ++of) {
            float* p = C + (size_t)n * DIM + of * 16 + obase;
            if (acc_mode) {
                p[0] += acc[of].x; p[1] += acc[of].y; p[2] += acc[of].z; p[3] += acc[of].w;
            } else {
                float4 vv = {acc[of].x, acc[of].y, acc[of].z, acc[of].w};
                *reinterpret_cast<float4*>(p) = vv;
            }
        }
    }
}

extern "C" void kernel_launch(void* const* d_in, const int* in_sizes, int n_in,
                              void* d_out, int out_size, void* d_ws, size_t ws_size,
                              hipStream_t stream) {
    const float* x     = (const float*)d_in[0];
    const int*   eidx  = (const int*)d_in[1];
    const int*   etype = (const int*)d_in[2];
    const float* norm  = (const float*)d_in[3];
    const float* selfW = (const float*)d_in[4];
    const float* bases = (const float*)d_in[5];
    const float* bw    = (const float*)d_in[6];
    float* out = (float*)d_out;

    // ---- workspace layout (all 256B aligned) ----
    char* p = (char*)d_ws;
    auto alloc = [&](size_t bytes) { char* q = p; p += (bytes + 255) & ~(size_t)255; return q; };
    unsigned short* Wt       = (unsigned short*)alloc((size_t)DIM * KTOT * 2);          // 0.69 MB
    unsigned short* xb       = (unsigned short*)alloc((size_t)N_NODES * DIM * 2);       // 12.8 MB
    unsigned short* agg      = (unsigned short*)alloc((size_t)N_NODES * RC * DIM * 2);  // 64 MB
    unsigned int*   sorted   = (unsigned int*)alloc((size_t)N_EDGES * 4);               // 6.4 MB
    unsigned int*   binstart = (unsigned int*)alloc((size_t)(NBINS + 1) * 4);           // 0.8 MB
    unsigned int*   cursor   = (unsigned int*)alloc((size_t)NBINS * 4);                 // 0.8 MB
    unsigned int*   totals   = (unsigned int*)alloc((size_t)SCAN_BLOCKS * 4);
    (void)ws_size;

    // 1. prep
    {
        int total = DIM * (N_REL + 1) * DIM;
        compute_wt<<<dim3((total + 255) / 256), dim3(256), 0, stream>>>(bases, bw, selfW, Wt);
        total = N_NODES * DIM;
        build_xb<<<dim3((total + 255) / 256), dim3(256), 0, stream>>>(x, xb);
    }

    // 2. counting sort by (chunk, dst)
    hipMemsetAsync(binstart, 0, (size_t)(NBINS + 1) * 4, stream);
    hist_kernel<<<dim3((N_EDGES + 255) / 256), dim3(256), 0, stream>>>(eidx, etype, binstart);
    scan1<<<dim3(SCAN_BLOCKS), dim3(SCAN_T), 0, stream>>>(binstart, totals);
    scan2<<<dim3(1), dim3(64), 0, stream>>>(totals);
    scan3<<<dim3((NBINS + 255) / 256), dim3(256), 0, stream>>>(binstart, cursor, totals);
    place_kernel<<<dim3((N_EDGES + 255) / 256), dim3(256), 0, stream>>>(eidx, etype, cursor, sorted);

    int gblocks = (N_NODES + 63) / 64;

    // 3. self-loop: out = x @ self_W.T (init write)
    gemm_bf<<<dim3(gblocks), dim3(256), 0, stream>>>(Wt + N_REL * DIM, xb, DIM, out, 0);

    // 4. per chunk: segmented reduce (atomic-free) + GEMM accumulate
    for (int c = 0; c < NCHUNK; ++c) {
        reduce_seg<<<dim3(N_NODES), dim3(128), 0, stream>>>(sorted, binstart, xb, norm, agg, c);
        gemm_bf<<<dim3(gblocks), dim3(256), 0, stream>>>(Wt + c * RC * DIM, agg, RC * DIM, out, 1);
    }
}

// Round 3
// 480.581 us; speedup vs baseline: 6.2354x; 1.2732x over previous
//
#include <hip/hip_runtime.h>
#include <hip/hip_bf16.h>

#define N_NODES 50000
#define N_EDGES 1600000
#define N_REL   20
#define N_BASIS 16
#define DIM     128
#define KTOT    ((N_REL + 1) * DIM)      // 2688 : Wt row stride (R rels + self)

#define RC      5                        // relations per chunk
#define NCHUNK  (N_REL / RC)             // 4
#define NBINS   (NCHUNK * N_NODES)       // 200000 sort bins: key = chunk*N + dst

#define CB_BITS      10
#define KEYS_PER_CB  (1 << CB_BITS)                              // 1024
#define NCB          ((NBINS + KEYS_PER_CB - 1) >> CB_BITS)      // 196 coarse buckets
#define EB           4096                                        // edges per sort block
#define SORT_BLOCKS  ((N_EDGES + EB - 1) / EB)                   // 391

typedef __attribute__((ext_vector_type(8))) short          bf16x8;
typedef __attribute__((ext_vector_type(4))) float          f32x4;
typedef __attribute__((ext_vector_type(8))) unsigned short ushort8v;

static __device__ __forceinline__ unsigned short f2bf(float f) {
    union { float f; unsigned int u; } v; v.f = f;
    unsigned int r = (v.u + 0x7FFFu + ((v.u >> 16) & 1u)) >> 16;   // RNE
    return (unsigned short)r;
}
static __device__ __forceinline__ float bf2f(unsigned short s) {
    union { unsigned int u; float f; } v; v.u = ((unsigned int)s) << 16;
    return v.f;
}

// ---------- prep: Wt[o][r*128+i] bf16 (r==N_REL -> self_W), xb = bf16(x) ----------
__global__ void compute_wt(const float* __restrict__ bases,
                           const float* __restrict__ bw,
                           const float* __restrict__ selfW,
                           unsigned short* __restrict__ Wt) {
    int t = blockIdx.x * blockDim.x + threadIdx.x;
    const int total = DIM * (N_REL + 1) * DIM;
    if (t >= total) return;
    int i = t & (DIM - 1);
    int r = (t >> 7) % (N_REL + 1);
    int o = t / (DIM * (N_REL + 1));
    float v;
    if (r < N_REL) {
        v = 0.f;
        #pragma unroll
        for (int b = 0; b < N_BASIS; ++b)
            v += bw[r * N_BASIS + b] * bases[((size_t)b * DIM + i) * DIM + o];
    } else {
        v = selfW[o * DIM + i];
    }
    Wt[(size_t)o * KTOT + r * DIM + i] = f2bf(v);
}

__global__ void build_xb(const float* __restrict__ x, unsigned short* __restrict__ xb) {
    int t = blockIdx.x * blockDim.x + threadIdx.x;
    const int total = N_NODES * DIM;
    if (t < total) xb[t] = f2bf(x[t]);
}

// ---------- two-level LDS-staged counting sort by key = (etype/RC)*N + dst ----------
// K1: coarse histogram (196 buckets of 1024 keys)
__global__ __launch_bounds__(256) void hist_coarse(const int* __restrict__ eidx,
                                                   const int* __restrict__ etype,
                                                   unsigned int* __restrict__ btot) {
    __shared__ unsigned int h[NCB];
    for (int i = threadIdx.x; i < NCB; i += 256) h[i] = 0;
    __syncthreads();
    int base = blockIdx.x * EB;
    #pragma unroll
    for (int k = 0; k < EB / 256; ++k) {
        int e = base + k * 256 + threadIdx.x;
        if (e < N_EDGES) {
            int r = etype[e];
            int dst = eidx[N_EDGES + e];
            int key = (r / RC) * N_NODES + dst;
            atomicAdd(&h[key >> CB_BITS], 1u);
        }
    }
    __syncthreads();
    for (int i = threadIdx.x; i < NCB; i += 256)
        if (h[i]) atomicAdd(&btot[i], h[i]);
}

// K2: scan coarse totals -> bucket bases/cursors + sentinels
__global__ __launch_bounds__(256) void scan_coarse(const unsigned int* __restrict__ btot,
                                                   unsigned int* __restrict__ cbase,
                                                   unsigned int* __restrict__ ccur,
                                                   unsigned int* __restrict__ binstart) {
    __shared__ unsigned int lds[256];
    int t = threadIdx.x;
    unsigned int v = (t < NCB) ? btot[t] : 0u;
    lds[t] = v; __syncthreads();
    for (int off = 1; off < 256; off <<= 1) {
        unsigned int a = (t >= off) ? lds[t - off] : 0u;
        __syncthreads();
        lds[t] += a;
        __syncthreads();
    }
    unsigned int excl = lds[t] - v;
    if (t < NCB) { cbase[t] = excl; ccur[t] = excl; }
    if (t == NCB - 1) cbase[NCB] = lds[t];        // == N_EDGES
    if (t == 0) binstart[NBINS] = N_EDGES;        // global sentinel
}

// K3: coarse place — per-block private contiguous runs per bucket
__global__ __launch_bounds__(256) void place_coarse(const int* __restrict__ eidx,
                                                    const int* __restrict__ etype,
                                                    unsigned int* __restrict__ ccur,
                                                    unsigned int* __restrict__ ebuf) {
    __shared__ unsigned int h[NCB];
    __shared__ unsigned int cur[NCB];
    for (int i = threadIdx.x; i < NCB; i += 256) h[i] = 0;
    __syncthreads();
    int base = blockIdx.x * EB;
    #pragma unroll
    for (int k = 0; k < EB / 256; ++k) {
        int e = base + k * 256 + threadIdx.x;
        if (e < N_EDGES) {
            int r = etype[e];
            int dst = eidx[N_EDGES + e];
            int key = (r / RC) * N_NODES + dst;
            atomicAdd(&h[key >> CB_BITS], 1u);
        }
    }
    __syncthreads();
    for (int i = threadIdx.x; i < NCB; i += 256)
        cur[i] = atomicAdd(&ccur[i], h[i]);       // reserve private run
    __syncthreads();
    #pragma unroll
    for (int k = 0; k < EB / 256; ++k) {
        int e = base + k * 256 + threadIdx.x;
        if (e < N_EDGES) {
            int r = etype[e];
            int src = eidx[e];
            int dst = eidx[N_EDGES + e];
            int c = r / RC;
            int rl = r - c * RC;
            int key = c * N_NODES + dst;
            int cb = key >> CB_BITS;
            unsigned int klo = (unsigned int)(key & (KEYS_PER_CB - 1));
            unsigned int pos = atomicAdd(&cur[cb], 1u);
            ebuf[pos] = (klo << 19) | ((unsigned int)rl << 16) | (unsigned int)src;
        }
    }
}

// K4: fine place within each bucket (one block per bucket) + binstart
__global__ __launch_bounds__(256) void place_fine(const unsigned int* __restrict__ cbase,
                                                  const unsigned int* __restrict__ ebuf,
                                                  unsigned int* __restrict__ sorted,
                                                  unsigned int* __restrict__ binstart) {
    __shared__ unsigned int h[KEYS_PER_CB];
    __shared__ unsigned int cur[KEYS_PER_CB];
    __shared__ unsigned int pscan[256];
    int b = blockIdx.x;
    int t = threadIdx.x;
    unsigned int s = cbase[b], e = cbase[b + 1];
    #pragma unroll
    for (int q = 0; q < 4; ++q) h[t * 4 + q] = 0;
    __syncthreads();
    for (unsigned int j = s + t; j < e; j += 256) {
        unsigned int v = ebuf[j];
        atomicAdd(&h[v >> 19], 1u);
    }
    __syncthreads();
    // scan 1024 counters: 4 serial per thread + block scan of partials
    unsigned int c0 = h[4 * t], c1 = h[4 * t + 1], c2 = h[4 * t + 2], c3 = h[4 * t + 3];
    unsigned int part = c0 + c1 + c2 + c3;
    pscan[t] = part; __syncthreads();
    for (int off = 1; off < 256; off <<= 1) {
        unsigned int a = (t >= off) ? pscan[t - off] : 0u;
        __syncthreads();
        pscan[t] += a;
        __syncthreads();
    }
    unsigned int ex = pscan[t] - part;
    unsigned int st0 = ex, st1 = ex + c0, st2 = st1 + c1, st3 = st2 + c2;
    h[4 * t] = st0; h[4 * t + 1] = st1; h[4 * t + 2] = st2; h[4 * t + 3] = st3;
    cur[4 * t] = st0; cur[4 * t + 1] = st1; cur[4 * t + 2] = st2; cur[4 * t + 3] = st3;
    int keyb = b * KEYS_PER_CB + 4 * t;
    if (keyb + 0 < NBINS) binstart[keyb + 0] = s + st0;
    if (keyb + 1 < NBINS) binstart[keyb + 1] = s + st1;
    if (keyb + 2 < NBINS) binstart[keyb + 2] = s + st2;
    if (keyb + 3 < NBINS) binstart[keyb + 3] = s + st3;
    __syncthreads();
    for (unsigned int j = s + t; j < e; j += 256) {
        unsigned int v = ebuf[j];
        unsigned int klo = v >> 19;
        unsigned int pos = s + atomicAdd(&cur[klo], 1u);
        sorted[pos] = v & 0x7FFFFu;               // (rl<<16 | src)
    }
}

// ---------- atomic-free segmented reduce: agg[dst][rl*128+i] = bf16( sum x[src][i]/norm ) ----------
__global__ __launch_bounds__(128) void reduce_seg(const unsigned int* __restrict__ sorted,
                                                  const unsigned int* __restrict__ binstart,
                                                  const unsigned short* __restrict__ xb,
                                                  const float* __restrict__ norm,
                                                  unsigned short* __restrict__ agg,
                                                  int chunk) {
    __shared__ float nlds[RC];
    int dst = blockIdx.x;
    int i = threadIdx.x;
    if (i < RC) nlds[i] = 1.0f / norm[(size_t)(chunk * RC + i) * N_NODES + dst];
    int key = chunk * N_NODES + dst;
    unsigned int bs = binstart[key], be = binstart[key + 1];
    __syncthreads();
    float a0 = 0.f, a1 = 0.f, a2 = 0.f, a3 = 0.f, a4 = 0.f;
    for (unsigned int j = bs; j < be; ++j) {
        unsigned int p = sorted[j];
        int src = p & 0xFFFF;
        int rl = p >> 16;
        float v = bf2f(xb[src * DIM + i]) * nlds[rl];
        a0 += (rl == 0) ? v : 0.f;
        a1 += (rl == 1) ? v : 0.f;
        a2 += (rl == 2) ? v : 0.f;
        a3 += (rl == 3) ? v : 0.f;
        a4 += (rl == 4) ? v : 0.f;
    }
    size_t ob = (size_t)dst * (RC * DIM) + i;
    agg[ob]           = f2bf(a0);
    agg[ob + DIM]     = f2bf(a1);
    agg[ob + 2 * DIM] = f2bf(a2);
    agg[ob + 3 * DIM] = f2bf(a3);
    agg[ob + 4 * DIM] = f2bf(a4);
}

// ---------- MFMA GEMM: out[n][o] (+)= sum_k Wt_sub[o*KTOT+k] * Bsrc[n*K+k], Bsrc bf16 ----------
__global__ __launch_bounds__(256) void gemm_bf(const unsigned short* __restrict__ Wt_sub,
                                               const unsigned short* __restrict__ Bsrc,
                                               int K,
                                               float* __restrict__ C,
                                               int acc_mode) {
    __shared__ __align__(16) unsigned short Ws[128 * 40];  // [o][k], pad stride 40
    __shared__ __align__(16) unsigned short As[64 * 40];   // [n][k]

    int tid  = threadIdx.x;
    int lane = tid & 63;
    int wv   = tid >> 6;
    int nblock = blockIdx.x * 64;

    f32x4 acc[8];
    #pragma unroll
    for (int i = 0; i < 8; ++i) acc[i] = (f32x4){0.f, 0.f, 0.f, 0.f};

    for (int k0 = 0; k0 < K; k0 += 32) {
        #pragma unroll
        for (int rep = 0; rep < 2; ++rep) {          // Wt tile: 128 o x 32 k
            int idx = rep * 256 + tid;
            int o  = idx >> 2;
            int kq = idx & 3;
            ushort8v v = *reinterpret_cast<const ushort8v*>(Wt_sub + (size_t)o * KTOT + k0 + kq * 8);
            *reinterpret_cast<ushort8v*>(&Ws[o * 40 + kq * 8]) = v;
        }
        {                                            // B tile: 64 n x 32 k
            int n  = tid >> 2;
            int kq = tid & 3;
            int gn = nblock + n;
            ushort8v v = (ushort8v){0,0,0,0,0,0,0,0};
            if (gn < N_NODES)
                v = *reinterpret_cast<const ushort8v*>(Bsrc + (size_t)gn * K + k0 + kq * 8);
            *reinterpret_cast<ushort8v*>(&As[n * 40 + kq * 8]) = v;
        }
        __syncthreads();

        int koff = (lane >> 4) * 8;
        int r16  = lane & 15;
        bf16x8 bfr = *reinterpret_cast<const bf16x8*>(&As[(wv * 16 + r16) * 40 + koff]);
        #pragma unroll
        for (int of = 0; of < 8; ++of) {
            bf16x8 afr = *reinterpret_cast<const bf16x8*>(&Ws[(of * 16 + r16) * 40 + koff]);
            acc[of] = __builtin_amdgcn_mfma_f32_16x16x32_bf16(afr, bfr, acc[of], 0, 0, 0);
        }
        __syncthreads();
    }

    int n = nblock + wv * 16 + (lane & 15);
    if (n < N_NODES) {
        int obase = (lane >> 4) * 4;
        #pragma unroll
        for (int of = 0; of < 8; ++of) {
            float* p = C + (size_t)n * DIM + of * 16 + obase;
            if (acc_mode) {
                p[0] += acc[of].x; p[1] += acc[of].y; p[2] += acc[of].z; p[3] += acc[of].w;
            } else {
                float4 vv = {acc[of].x, acc[of].y, acc[of].z, acc[of].w};
                *reinterpret_cast<float4*>(p) = vv;
            }
        }
    }
}

extern "C" void kernel_launch(void* const* d_in, const int* in_sizes, int n_in,
                              void* d_out, int out_size, void* d_ws, size_t ws_size,
                              hipStream_t stream) {
    const float* x     = (const float*)d_in[0];
    const int*   eidx  = (const int*)d_in[1];
    const int*   etype = (const int*)d_in[2];
    const float* norm  = (const float*)d_in[3];
    const float* selfW = (const float*)d_in[4];
    const float* bases = (const float*)d_in[5];
    const float* bw    = (const float*)d_in[6];
    float* out = (float*)d_out;

    // ---- workspace layout (256B aligned) ----
    char* p = (char*)d_ws;
    auto alloc = [&](size_t bytes) { char* q = p; p += (bytes + 255) & ~(size_t)255; return q; };
    unsigned short* Wt       = (unsigned short*)alloc((size_t)DIM * KTOT * 2);          // 0.69 MB
    unsigned short* xb       = (unsigned short*)alloc((size_t)N_NODES * DIM * 2);       // 12.8 MB
    unsigned short* agg      = (unsigned short*)alloc((size_t)N_NODES * RC * DIM * 2);  // 64 MB
    unsigned int*   sorted   = (unsigned int*)alloc((size_t)N_EDGES * 4);               // 6.4 MB
    unsigned int*   binstart = (unsigned int*)alloc((size_t)(NBINS + 1) * 4);           // 0.8 MB
    unsigned int*   btot     = (unsigned int*)alloc((size_t)NCB * 4);
    unsigned int*   cbase    = (unsigned int*)alloc((size_t)(NCB + 1) * 4);
    unsigned int*   ccur     = (unsigned int*)alloc((size_t)NCB * 4);
    unsigned int*   ebuf     = (unsigned int*)agg;   // alias: ebuf dead before agg is written
    (void)ws_size;

    // 1. prep
    {
        int total = DIM * (N_REL + 1) * DIM;
        compute_wt<<<dim3((total + 255) / 256), dim3(256), 0, stream>>>(bases, bw, selfW, Wt);
        total = N_NODES * DIM;
        build_xb<<<dim3((total + 255) / 256), dim3(256), 0, stream>>>(x, xb);
    }

    // 2. two-level counting sort by (chunk, dst)
    hipMemsetAsync(btot, 0, (size_t)NCB * 4, stream);
    hist_coarse<<<dim3(SORT_BLOCKS), dim3(256), 0, stream>>>(eidx, etype, btot);
    scan_coarse<<<dim3(1), dim3(256), 0, stream>>>(btot, cbase, ccur, binstart);
    place_coarse<<<dim3(SORT_BLOCKS), dim3(256), 0, stream>>>(eidx, etype, ccur, ebuf);
    place_fine<<<dim3(NCB), dim3(256), 0, stream>>>(cbase, ebuf, sorted, binstart);

    int gblocks = (N_NODES + 63) / 64;

    // 3. self-loop: out = x @ self_W.T (init write)
    gemm_bf<<<dim3(gblocks), dim3(256), 0, stream>>>(Wt + N_REL * DIM, xb, DIM, out, 0);

    // 4. per chunk: segmented reduce (atomic-free) + GEMM accumulate
    for (int c = 0; c < NCHUNK; ++c) {
        reduce_seg<<<dim3(N_NODES), dim3(128), 0, stream>>>(sorted, binstart, xb, norm, agg, c);
        gemm_bf<<<dim3(gblocks), dim3(256), 0, stream>>>(Wt + c * RC * DIM, agg, RC * DIM, out, 1);
    }
}